// Round 10
// baseline (4167.933 us; speedup 1.0000x reference)
//
#include <hip/hip_runtime.h>
#include <hip/hip_bf16.h>

#define T_STEPS 48
#define B_SZ    64
#define H_IN    64
#define W_IN    64
#define OC      16
#define KH      7
#define KW      7
#define STRIDEC 2
#define HO      29
#define WO      29
#define IN_SZ   13456
#define N_NEU   1000
#define N_PAD   1024

// ---------------- ws layout (bytes) ----------------
#define WT_OFF    0ull                 // WlsmT padded [1000][1024] f32 = 4,096,000
#define CURR_OFF  4096000ull           // curr [48][64][1024] f32 = 12,582,912
#define SYN_OFF   16678912ull          // (unused by fused steps, kept)
#define MEM_OFF   16941056ull
#define MASK_OFF  17203200ull
#define G_OFF     17219584ull          // conv output buffer

// ---------------- Wlsm transpose: WT[m][n] = Wlsm[n][m], zero-pad n>=1000 ----
__global__ __launch_bounds__(256) void transpose_wlsm(const float* __restrict__ Wlsm,
                                                      float* __restrict__ WT) {
  __shared__ float t[32][33];
  const int m0 = blockIdx.x * 32;
  const int n0 = blockIdx.y * 32;
  const int tx = threadIdx.x & 31, ty = threadIdx.x >> 5;  // 32 x 8
  #pragma unroll
  for (int j = 0; j < 4; ++j) {
    int n = n0 + ty + j * 8, m = m0 + tx;
    t[ty + j * 8][tx] = (n < N_NEU && m < N_NEU) ? Wlsm[n * N_NEU + m] : 0.f;
  }
  __syncthreads();
  #pragma unroll
  for (int j = 0; j < 4; ++j) {
    int m = m0 + ty + j * 8, n = n0 + tx;
    if (m < N_NEU) WT[(size_t)m * N_PAD + n] = t[tx][ty + j * 8];
  }
}

// ---------------- Gabor conv: one block per image (verbatim) ----------------
__global__ __launch_bounds__(256) void conv_kernel(const float* __restrict__ x,
                                                   const float* __restrict__ w,
                                                   float* __restrict__ g,
                                                   int img0) {
  __shared__ float img[H_IN * W_IN];
  const int blk = blockIdx.x;
  const float* xim = x + (size_t)(img0 + blk) * (H_IN * W_IN);
  for (int i = threadIdx.x; i < (H_IN * W_IN) / 4; i += 256)
    ((float4*)img)[i] = ((const float4*)xim)[i];
  __syncthreads();
  float* gout = g + (size_t)blk * IN_SZ;
  for (int pos = threadIdx.x; pos < HO * WO; pos += 256) {
    const int oh = pos / WO, ow = pos - oh * WO;
    const int ih = oh * STRIDEC, iw = ow * STRIDEC;
    float acc[OC];
    #pragma unroll
    for (int oc = 0; oc < OC; ++oc) acc[oc] = 0.f;
    #pragma unroll
    for (int kh = 0; kh < KH; ++kh) {
      #pragma unroll
      for (int kw = 0; kw < KW; ++kw) {
        const float v = img[(ih + kh) * W_IN + iw + kw];
        const int widx = kh * KW + kw;
        #pragma unroll
        for (int oc = 0; oc < OC; ++oc)
          acc[oc] += v * w[oc * (KH * KW) + widx];
      }
    }
    #pragma unroll
    for (int oc = 0; oc < OC; ++oc)
      gout[oc * (HO * WO) + pos] = acc[oc];
  }
}

// ---------------- fp32 GEMM v5 (R9 verbatim, PASSED bit-exact) --------------
#define BM5 64
#define BN5 64
#define BK5 32
#define LDA5 68
#define LDB5 68
__global__ __launch_bounds__(256) void gemm_kernel(const float* __restrict__ A,
                                                   int row_off,
                                                   const float* __restrict__ Wins,
                                                   const float* __restrict__ fc1_b,
                                                   float* __restrict__ curr) {
  __shared__ __align__(16) float As[BK5 * LDA5];
  __shared__ __align__(16) float Bs[BK5 * LDB5];
  const int tid = threadIdx.x;
  const int n0 = blockIdx.x * BN5;
  const int row_l0 = blockIdx.y * BM5;
  const int r0 = (tid >> 4) * 4;
  const int c0 = (tid & 15) * 4;
  const int p = (row_off + row_l0) / 768;
  const float* Bp = Wins + (size_t)p * N_NEU * IN_SZ;

  float acc[4][4];
  #pragma unroll
  for (int i = 0; i < 4; ++i)
    #pragma unroll
    for (int j = 0; j < 4; ++j) acc[i][j] = 0.f;

  for (int k0 = 0; k0 < IN_SZ; k0 += BK5) {
    #pragma unroll
    for (int it = 0; it < 2; ++it) {
      const int f = it * 256 + tid;
      const int rr = f >> 3;
      const int kq = (f & 7) * 4;
      const int k = k0 + kq;
      float4 va = make_float4(0.f, 0.f, 0.f, 0.f);
      if (k < IN_SZ)
        va = *(const float4*)(A + (size_t)(row_l0 + rr) * IN_SZ + k);
      As[(kq + 0) * LDA5 + rr] = va.x;
      As[(kq + 1) * LDA5 + rr] = va.y;
      As[(kq + 2) * LDA5 + rr] = va.z;
      As[(kq + 3) * LDA5 + rr] = va.w;
    }
    #pragma unroll
    for (int it = 0; it < 2; ++it) {
      const int f = it * 256 + tid;
      const int cc = f >> 3;
      const int kq = (f & 7) * 4;
      const int k = k0 + kq;
      float4 vb = make_float4(0.f, 0.f, 0.f, 0.f);
      if (k < IN_SZ && n0 + cc < N_NEU)
        vb = *(const float4*)(Bp + (size_t)(n0 + cc) * IN_SZ + k);
      Bs[(kq + 0) * LDB5 + cc] = vb.x;
      Bs[(kq + 1) * LDB5 + cc] = vb.y;
      Bs[(kq + 2) * LDB5 + cc] = vb.z;
      Bs[(kq + 3) * LDB5 + cc] = vb.w;
    }
    __syncthreads();

    float lacc[4][4];
    #pragma unroll
    for (int i = 0; i < 4; ++i)
      #pragma unroll
      for (int j = 0; j < 4; ++j) lacc[i][j] = 0.f;
    #pragma unroll
    for (int kk = 0; kk < BK5; ++kk) {
      const float4 a0 = *(const float4*)&As[kk * LDA5 + r0];
      const float4 b0 = *(const float4*)&Bs[kk * LDB5 + c0];
      const float a[4] = {a0.x, a0.y, a0.z, a0.w};
      const float bb[4] = {b0.x, b0.y, b0.z, b0.w};
      #pragma unroll
      for (int i = 0; i < 4; ++i)
        #pragma unroll
        for (int j = 0; j < 4; ++j) lacc[i][j] += a[i] * bb[j];
    }
    #pragma unroll
    for (int i = 0; i < 4; ++i)
      #pragma unroll
      for (int j = 0; j < 4; ++j) acc[i][j] += lacc[i][j];
    __syncthreads();
  }

  const int g_row_base = row_off + row_l0 + r0;
  #pragma unroll
  for (int i = 0; i < 4; ++i) {
    float* crow = curr + ((size_t)(g_row_base + i) << 10);
    float4 o;
    const int nn = n0 + c0;
    o.x = acc[i][0] + fc1_b[nn + 0 < N_NEU ? nn + 0 : (N_NEU - 1)];
    o.y = acc[i][1] + fc1_b[nn + 1 < N_NEU ? nn + 1 : (N_NEU - 1)];
    o.z = acc[i][2] + fc1_b[nn + 2 < N_NEU ? nn + 2 : (N_NEU - 1)];
    o.w = acc[i][3] + fc1_b[nn + 3 < N_NEU ? nn + 3 : (N_NEU - 1)];
    *(float4*)(crow + nn) = o;
  }
}

// ---------------- fused recurrence: ALL 48 steps in one kernel --------------
// grid 64 (one block per batch) x 1024 threads (one neuron each).
// Per-neuron FP chain bit-identical to R9: 8 gather partials p_g over rows
// j==g (mod 8) ascending, combined sequentially p0+p1+...+p7; same syn/mem
// expressions. Spike masks live in LDS; states live in registers.
__global__ __launch_bounds__(1024) void steps_fused(
    const float* __restrict__ WT, const float* __restrict__ curr,
    const float* __restrict__ rec_b, float* __restrict__ out) {
  __shared__ unsigned long long smask[16];
  __shared__ int idxs[1024];
  __shared__ int cnts[16];
  __shared__ int offs[17];
  const int tid = threadIdx.x;
  const int b = blockIdx.x;
  const int n = tid;
  const int wid = tid >> 6, lane = tid & 63;
  float syn = 0.f, mem = 0.f;
  const float rbv = (n < N_NEU) ? rec_b[n] : 0.f;
  const float* wtn = WT + n;
  if (tid < 16) smask[tid] = 0ull;

  for (int t = 0; t < T_STEPS; ++t) {
    __syncthreads();                       // prev-step masks visible
    if (tid < 16) cnts[tid] = (int)__popcll(smask[tid]);
    __syncthreads();
    if (tid == 0) {
      int o = 0;
      #pragma unroll
      for (int c = 0; c < 16; ++c) { offs[c] = o; o += cnts[c]; }
      offs[16] = o;
    }
    __syncthreads();
    if (tid < 16) {
      unsigned long long s = smask[tid];
      int o = offs[tid];
      const int base = tid << 6;
      while (s) {
        idxs[o++] = base + __builtin_ctzll(s);
        s &= s - 1;
      }
    }
    __syncthreads();                       // idxs ready; smask reads done
    const int L = offs[16];

    // gather: 8 independent chains (groups j mod 8), ascending within group
    float p0 = 0.f, p1 = 0.f, p2 = 0.f, p3 = 0.f;
    float p4 = 0.f, p5 = 0.f, p6 = 0.f, p7 = 0.f;
    int j = 0;
    for (; j + 8 <= L; j += 8) {
      const int m0 = idxs[j + 0], m1 = idxs[j + 1], m2 = idxs[j + 2], m3 = idxs[j + 3];
      const int m4 = idxs[j + 4], m5 = idxs[j + 5], m6 = idxs[j + 6], m7 = idxs[j + 7];
      p0 += wtn[(size_t)m0 << 10];
      p1 += wtn[(size_t)m1 << 10];
      p2 += wtn[(size_t)m2 << 10];
      p3 += wtn[(size_t)m3 << 10];
      p4 += wtn[(size_t)m4 << 10];
      p5 += wtn[(size_t)m5 << 10];
      p6 += wtn[(size_t)m6 << 10];
      p7 += wtn[(size_t)m7 << 10];
    }
    const int rem = L - j;
    if (rem > 0) p0 += wtn[(size_t)idxs[j + 0] << 10];
    if (rem > 1) p1 += wtn[(size_t)idxs[j + 1] << 10];
    if (rem > 2) p2 += wtn[(size_t)idxs[j + 2] << 10];
    if (rem > 3) p3 += wtn[(size_t)idxs[j + 3] << 10];
    if (rem > 4) p4 += wtn[(size_t)idxs[j + 4] << 10];
    if (rem > 5) p5 += wtn[(size_t)idxs[j + 5] << 10];
    if (rem > 6) p6 += wtn[(size_t)idxs[j + 6] << 10];
    float rec = p0;
    rec += p1; rec += p2; rec += p3; rec += p4; rec += p5; rec += p6; rec += p7;

    const float cv = curr[((size_t)t << 16) + ((size_t)b << 10) + n];
    syn = 0.9f * syn + cv + rec + rbv;
    const float reset = (mem - 1.0f > 0.f) ? 1.0f : 0.f;
    mem = 0.9f * mem + syn - reset;
    const int spk = ((mem - 1.0f) > 0.f && n < N_NEU) ? 1 : 0;
    if (n < N_NEU) out[(size_t)t * 64000 + b * 1000 + n] = (float)spk;
    const unsigned long long bal = __ballot(spk);
    if (lane == 0) smask[wid] = bal;       // next loop-top barrier publishes
  }
}

extern "C" void kernel_launch(void* const* d_in, const int* in_sizes, int n_in,
                              void* d_out, int out_size, void* d_ws, size_t ws_size,
                              hipStream_t stream) {
  const float* x     = (const float*)d_in[0];
  const float* gw    = (const float*)d_in[1];
  const float* Wins  = (const float*)d_in[2];
  const float* fc1_b = (const float*)d_in[3];
  const float* Wlsm  = (const float*)d_in[4];
  const float* rec_b = (const float*)d_in[5];
  float* out = (float*)d_out;
  char* ws = (char*)d_ws;

  float* WT   = (float*)(ws + WT_OFF);
  float* curr = (float*)(ws + CURR_OFF);
  float* gbuf = (float*)(ws + G_OFF);

  hipLaunchKernelGGL(transpose_wlsm, dim3(32, 32), dim3(256), 0, stream, Wlsm, WT);

  const size_t needA = G_OFF + (size_t)3072 * IN_SZ * 4;
  if (ws_size >= needA) {
    hipLaunchKernelGGL(conv_kernel, dim3(3072), dim3(256), 0, stream, x, gw, gbuf, 0);
    hipLaunchKernelGGL(gemm_kernel, dim3(16, 48), dim3(256), 0, stream,
                       gbuf, 0, Wins, fc1_b, curr);
  } else {
    for (int p = 0; p < 4; ++p) {
      hipLaunchKernelGGL(conv_kernel, dim3(768), dim3(256), 0, stream,
                         x, gw, gbuf, p * 768);
      hipLaunchKernelGGL(gemm_kernel, dim3(16, 12), dim3(256), 0, stream,
                         gbuf, p * 768, Wins, fc1_b, curr);
    }
  }

  hipLaunchKernelGGL(steps_fused, dim3(64), dim3(1024), 0, stream,
                     WT, curr, rec_b, out);
}